// Round 2
// baseline (575.639 us; speedup 1.0000x reference)
//
#include <hip/hip_runtime.h>

// SpanMaxPooler: B=32, S=4096, H=1024, K=2
// out[b, k*H + h] = max over s in [start[b,k], end[b,k]) of hidden[b,s,h],
//                   or missing_embeddings[k,h] if span missing (start<0 || end<0).
//
// Structure: 256 blocks (one per CU): (b,k) x 4 column-chunks of 256 cols.
// Block = 256 threads = 4 waves; wave w handles rows st+w, st+w+4, ...
// Each lane: 4 contiguous cols via float4 (1 KB per row-chunk per wave, coalesced).
// Row loop unrolled x4 with 4 independent accumulators (dep-chain cut);
// bound checks are wave-uniform (st/en/s uniform) -> scalar branches, no divergence.

#define B_ 32
#define S_ 4096
#define H_ 1024
#define K_ 2
#define CHUNKS 4
#define NEG_INF (-3.4028234663852886e38f)

__device__ __forceinline__ float4 f4max(float4 a, float4 b) {
  return make_float4(fmaxf(a.x, b.x), fmaxf(a.y, b.y),
                     fmaxf(a.z, b.z), fmaxf(a.w, b.w));
}

__global__ __launch_bounds__(256) void span_max_kernel(
    const float* __restrict__ hidden,   // [B,S,H]
    const int*   __restrict__ start,    // [B,K]
    const int*   __restrict__ end,      // [B,K]
    const float* __restrict__ miss,     // [K,H]
    float*       __restrict__ out) {    // [B,K*H]
  const int blk   = blockIdx.x;
  const int chunk = blk & (CHUNKS - 1);
  const int bk    = blk >> 2;            // = b*K + k
  const int k     = bk & (K_ - 1);
  const int b     = bk >> 1;

  const int wave = threadIdx.x >> 6;     // 0..3 row groups
  const int lane = threadIdx.x & 63;
  const int col  = chunk * 256 + lane * 4;

  const int st = start[bk];
  const int en = end[bk];

  float* outp = out + (size_t)bk * H_ + col;

  if (st < 0 || en < 0) {
    if (wave == 0) {
      *(float4*)outp = *(const float4*)(miss + (size_t)k * H_ + col);
    }
    return;
  }

  const float* base = hidden + (size_t)b * S_ * H_ + col;
  const float4 ninf = make_float4(NEG_INF, NEG_INF, NEG_INF, NEG_INF);
  float4 a0 = ninf, a1 = ninf, a2 = ninf, a3 = ninf;

  // wave w owns rows {st+w, st+w+4, st+w+8, ...}; unroll 4 -> rows spaced 16.
  for (int s = st + wave; s < en; s += 16) {
    a0 = f4max(a0, *(const float4*)(base + (size_t)s * H_));
    if (s + 4 < en)  a1 = f4max(a1, *(const float4*)(base + (size_t)(s + 4)  * H_));
    if (s + 8 < en)  a2 = f4max(a2, *(const float4*)(base + (size_t)(s + 8)  * H_));
    if (s + 12 < en) a3 = f4max(a3, *(const float4*)(base + (size_t)(s + 12) * H_));
  }
  float4 acc = f4max(f4max(a0, a1), f4max(a2, a3));

  __shared__ float4 red[256];
  red[threadIdx.x] = acc;
  __syncthreads();

  if (wave == 0) {
    float4 a = red[lane];
    a = f4max(a, red[64 + lane]);
    a = f4max(a, red[128 + lane]);
    a = f4max(a, red[192 + lane]);
    *(float4*)outp = a;
  }
}

extern "C" void kernel_launch(void* const* d_in, const int* in_sizes, int n_in,
                              void* d_out, int out_size, void* d_ws, size_t ws_size,
                              hipStream_t stream) {
  const float* hidden = (const float*)d_in[0];
  const int*   start  = (const int*)d_in[1];
  const int*   end    = (const int*)d_in[2];
  const float* miss   = (const float*)d_in[3];
  float*       out    = (float*)d_out;

  span_max_kernel<<<dim3(B_ * K_ * CHUNKS), dim3(256), 0, stream>>>(
      hidden, start, end, miss, out);
}